// Round 11
// baseline (1347.613 us; speedup 1.0000x reference)
//
#include <hip/hip_runtime.h>
#include <hip/hip_bf16.h>
#include <stdint.h>

#define T_ 64
#define N_ 1024
#define L_ 128
#define H_ 512
#define C_ 64
#define S_ 771          // 1 + 1 + H + (L+1) + L
#define TN_ (T_*N_)

typedef unsigned short u16;
typedef unsigned int u32;
typedef float f32x4 __attribute__((ext_vector_type(4)));
typedef __bf16 bf16x8 __attribute__((ext_vector_type(8)));
typedef u16 u16x8 __attribute__((ext_vector_type(8)));
typedef u32 u32x4 __attribute__((ext_vector_type(4)));

#define WAITVM0() do { asm volatile("s_waitcnt vmcnt(0)" ::: "memory"); \
                       __builtin_amdgcn_sched_barrier(0); } while (0)

__device__ __forceinline__ u16 f2bf(float f) {
  u32 u = __float_as_uint(f);
  u32 r = (u + 0x7FFFu + ((u >> 16) & 1u)) >> 16;
  return (u16)r;
}
__device__ __forceinline__ float bf2f(u16 u) {
  return __uint_as_float(((u32)u) << 16);
}
__device__ __forceinline__ void gload16(const void* g, void* l) {
  __builtin_amdgcn_global_load_lds((const __attribute__((address_space(1))) u32*)g,
                                   (__attribute__((address_space(3))) u32*)l, 16, 0, 0);
}
__device__ __forceinline__ float sigm(float x) { return 1.0f / (1.0f + __expf(-x)); }
// fast tanh: 1 - 2/(1+e^{2x}); e^{2x}->inf gives 1, ->0 gives -1 (correct limits)
__device__ __forceinline__ float ftanh(float x) {
  return 1.0f - 2.0f / (1.0f + __expf(2.0f * x));
}

__device__ __forceinline__ u32x4 load_cc4(const int* p) {
  u32x4 v;
  asm volatile("global_load_dwordx4 %0, %1, off sc0 sc1" : "=v"(v) : "v"(p) : "memory");
  return v;
}
__device__ __forceinline__ void store_cc_d2(u16* p, uint2 val) {
  asm volatile("global_store_dwordx2 %0, %1, off sc0 sc1" :: "v"(p), "v"(val) : "memory");
}
__device__ __forceinline__ void store_cc_u32(int* p, u32 val) {
  asm volatile("global_store_dword %0, %1, off sc0 sc1" :: "v"(p), "v"(val) : "memory");
}
__device__ __forceinline__ float gi_get(uint2 u, int v) {
  u32 w = (v < 2) ? u.x : u.y;
  u16 h = (v & 1) ? (u16)(w >> 16) : (u16)(w & 0xffffu);
  return bf2f(h);
}

// ---------------- prep kernels ----------------
#define CA0 294912      // W0  512*576
#define CA1 557056      // W1  +512*512
#define CA2 819200      // W2  +512*512
#define CA3 1605632     // Wih +1536*512
#define CA4 2392064     // Whh +1536*512
#define CTOT 2424832    // emb +64*512
__global__ void cast_all(const float* __restrict__ W0, const float* __restrict__ W1,
                         const float* __restrict__ W2, const float* __restrict__ Wih,
                         const float* __restrict__ Whh, const float* __restrict__ emb,
                         u16* __restrict__ dst) {
  int i = blockIdx.x * 256 + threadIdx.x;
  if (i >= CTOT) return;
  float v;
  if (i < CA0)      v = W0[i];
  else if (i < CA1) v = W1[i - CA0];
  else if (i < CA2) v = W2[i - CA1];
  else if (i < CA3) v = Wih[i - CA2];
  else if (i < CA4) v = Whh[i - CA3];
  else              v = emb[i - CA4];
  dst[i] = f2bf(v);
}

__global__ void qscan(const float* __restrict__ hxs, const int* __restrict__ actions,
                      int* __restrict__ qpre, int* __restrict__ qpost) {
  int wave = threadIdx.x >> 6, lane = threadIdx.x & 63;
  int n = blockIdx.x * 4 + wave;
  int a_l = actions[lane * N_ + n];
  bool nz = false;
  for (int s = lane; s < S_; s += 64) nz |= (hxs[(size_t)n * S_ + s] != 0.0f);
  unsigned long long bal = __ballot(nz);
  int q = 0;
  if (bal) {
    float best = -3.4e38f; int bi = L_;
    for (int l = lane; l < L_; l += 64) {
      float v = hxs[(size_t)n * S_ + 2 + H_ + (L_ + 1) + l];
      if (v > best) { best = v; bi = l; }
    }
    for (int m = 32; m; m >>= 1) {
      float ob = __shfl_xor(best, m); int oi = __shfl_xor(bi, m);
      if (ob > best || (ob == best && oi < bi)) { best = ob; bi = oi; }
    }
    q = (bi < L_) ? bi : 0;
  }
  for (int t = 0; t < T_; ++t) {
    int a = __shfl(a_l, t);
    if (lane == 0) {
      qpre[t * N_ + n] = q;
      if (a < L_) q = a;
      qpost[t * N_ + n] = q;
    }
  }
}

__global__ void hbf_init(const float* __restrict__ hxs, u16* __restrict__ hsave0) {
  int i = blockIdx.x * 256 + threadIdx.x;
  if (i >= N_ * H_) return;
  int n = i >> 9, j = i & 511;
  hsave0[i] = f2bf(hxs[(size_t)n * S_ + 2 + j]);
}

// A = [cond_t | embb[lines[n, qpre]]] as bf16 (TN x 576); one wave per row
__global__ void build_abuf(const float* __restrict__ cond, const u16* __restrict__ embb,
                           const int* __restrict__ lines, const int* __restrict__ qpre,
                           u16* __restrict__ abuf) {
  int row = blockIdx.x * 4 + (threadIdx.x >> 6);
  int lane = threadIdx.x & 63;
  int n = row & (N_ - 1);
  int q = qpre[row];
  int line = lines[n * L_ + q];
  abuf[(size_t)row * 576 + lane] = f2bf(cond[(size_t)row * 64 + lane]);
  const u16* er = embb + (size_t)line * H_;
  u16* ar = abuf + (size_t)row * 576 + 64;
  for (int j = lane; j < H_; j += 64) ar[j] = er[j];
}

// ---------------- phase-A GEMM ----------------
#define BM 128
#define BN 128
#define BK 64
__global__ __launch_bounds__(256) void gemm_nt(
    const u16* __restrict__ A, int lda,
    const u16* __restrict__ B, int ldb,
    const float* __restrict__ bias,
    u16* __restrict__ C, int ldc,
    int K, int relu)
{
  __shared__ __align__(16) u16 lA[BM * BK];
  __shared__ __align__(16) u16 lB[BN * BK];
  int tid = threadIdx.x;
  int lane = tid & 63;
  int wave = tid >> 6;
  int wm = wave >> 1, wn = wave & 1;
  int m0 = blockIdx.y * BM;
  int n0 = blockIdx.x * BN;

  f32x4 acc[4][4];
  f32x4 zero = {0.f, 0.f, 0.f, 0.f};
#pragma unroll
  for (int i = 0; i < 4; ++i)
#pragma unroll
    for (int j = 0; j < 4; ++j) acc[i][j] = zero;

  int nkt = K / BK;
  for (int kt = 0; kt < nkt; ++kt) {
#pragma unroll
    for (int it = 0; it < 4; ++it) {
      int s = it * 256 + tid;
      int row = s >> 3, cs = s & 7;
      gload16(A + (size_t)(m0 + row) * lda + kt * BK + cs * 8,
              lA + (size_t)(it * 256 + (tid & ~63)) * 8);
      gload16(B + (size_t)(n0 + row) * ldb + kt * BK + cs * 8,
              lB + (size_t)(it * 256 + (tid & ~63)) * 8);
    }
    __syncthreads();
#pragma unroll
    for (int ks = 0; ks < 2; ++ks) {
      bf16x8 af[4], bfr[4];
#pragma unroll
      for (int fm = 0; fm < 4; ++fm) {
        int rowa = wm * 64 + fm * 16 + (lane & 15);
        af[fm] = *(const bf16x8*)&lA[rowa * BK + ks * 32 + ((lane >> 4) << 3)];
      }
#pragma unroll
      for (int fn = 0; fn < 4; ++fn) {
        int rowb = wn * 64 + fn * 16 + (lane & 15);
        bfr[fn] = *(const bf16x8*)&lB[rowb * BK + ks * 32 + ((lane >> 4) << 3)];
      }
#pragma unroll
      for (int fm = 0; fm < 4; ++fm)
#pragma unroll
        for (int fn = 0; fn < 4; ++fn)
          acc[fm][fn] = __builtin_amdgcn_mfma_f32_16x16x32_bf16(af[fm], bfr[fn], acc[fm][fn], 0, 0, 0);
    }
    __syncthreads();
  }
#pragma unroll
  for (int fm = 0; fm < 4; ++fm) {
#pragma unroll
    for (int fn = 0; fn < 4; ++fn) {
      int col = n0 + wn * 64 + fn * 16 + (lane & 15);
      float b = bias[col];
#pragma unroll
      for (int v = 0; v < 4; ++v) {
        int row = m0 + wm * 64 + fm * 16 + ((lane >> 4) << 2) + v;
        float val = acc[fm][fn][v] + b;
        if (relu) val = fmaxf(val, 0.0f);
        C[(size_t)row * ldc + col] = f2bf(val);
      }
    }
  }
}

// ---------------- phase-B: persistent GRU recurrence (2 WG/CU for TLP) ----------------
// 512 WGs = 16 mt (64 n) x 32 jt (16 j). 48KB LDS/WG -> 2 WG/CU, 2 waves/SIMD.
// Waves: 4 n-subtiles of 16 rows, full 16 j each. WHH chunk-transposed LDS
// (R9/R10-proven conflict-free). Hout/flags sc0sc1; Hin plain L2-cached (R10-proven).
__global__ __launch_bounds__(256, 2) void gru_persistent(
    const u16* __restrict__ GI,    // (TN,1536) bf16
    const u16* __restrict__ WHH,   // (1536,512) bf16
    u16* __restrict__ Hsave,       // (T_+1, N_, 512) bf16; slot 0 = h_init
    const float* __restrict__ hxs, // initial h f32 at [n*S_+2+j]
    const float* __restrict__ bhh, // (1536)
    int* __restrict__ bar)         // [16][32] zeroed before launch
{
  __shared__ __align__(1024) u16 lW[48 * 512];   // 48KB
  int tid = threadIdx.x;
  int lane = tid & 63;
  int wave = tid >> 6;
  int bid = blockIdx.x;
  int mt = bid & 15, jt = bid >> 4;    // jt in [0,32)
  int l15 = lane & 15, l4 = lane >> 4;
  int nw0 = mt * 64 + wave * 16;       // wave's 16 n-rows
  int j0 = jt * 16;                    // WG's 16 j-cols
  int jt4 = l4 * 4;

  // ---- stage WHH slice (3 gates x 16 j x 512 k) chunk-transposed: 48 x 1KB
  for (int c = wave; c < 48; c += 4) {
    int g = c >> 4, kk = c & 15;
    const u16* src = WHH + ((size_t)(g * 512 + j0 + l15)) * 512 + kk * 32 + l4 * 8;
    gload16(src, (char*)lW + c * 1024);
  }

  // ---- per-lane constants
  float bb[3][4];
  float hreg[4];
#pragma unroll
  for (int g = 0; g < 3; ++g)
#pragma unroll
    for (int v = 0; v < 4; ++v) bb[g][v] = bhh[g * 512 + j0 + jt4 + v];
#pragma unroll
  for (int v = 0; v < 4; ++v)
    hreg[v] = hxs[(size_t)(nw0 + l15) * S_ + 2 + j0 + jt4 + v];

  WAITVM0();
  __syncthreads();

  int* bmt = bar + mt * 32;

  for (int t = 0; t < T_; ++t) {
    const u16* Hin = Hsave + (size_t)t * (N_ * 512);
    u16* Hout = Hsave + (size_t)(t + 1) * (N_ * 512);
    const size_t tb = (size_t)t * N_;

    // ---- gi loads (plain), issued before the spin
    const u16* girow = GI + (tb + nw0 + l15) * 1536;
    uint2 giu[3];
#pragma unroll
    for (int g = 0; g < 3; ++g)
      giu[g] = *(const uint2*)(girow + g * 512 + j0 + jt4);

    if (t > 0) {
      if (tid == 0) {
        for (;;) {
          u32 m0v = 0xffffffffu;
#pragma unroll
          for (int q8 = 0; q8 < 8; ++q8) {
            u32x4 a = load_cc4(bmt + q8 * 4);
            if (q8 == 7) WAITVM0();
            // values used after full issue; wait once then reduce
            if (q8 == 7) {
              // nothing
            }
            (void)a;
          }
          // re-load with explicit waits (simple, 2 bursts)
          u32x4 a = load_cc4(bmt), b = load_cc4(bmt + 4);
          u32x4 c = load_cc4(bmt + 8), d = load_cc4(bmt + 12);
          u32x4 e = load_cc4(bmt + 16), f = load_cc4(bmt + 20);
          u32x4 g = load_cc4(bmt + 24), h = load_cc4(bmt + 28);
          WAITVM0();
#pragma unroll
          for (int i = 0; i < 4; ++i) {
            m0v = m0v < a[i] ? m0v : a[i]; m0v = m0v < b[i] ? m0v : b[i];
            m0v = m0v < c[i] ? m0v : c[i]; m0v = m0v < d[i] ? m0v : d[i];
            m0v = m0v < e[i] ? m0v : e[i]; m0v = m0v < f[i] ? m0v : f[i];
            m0v = m0v < g[i] ? m0v : g[i]; m0v = m0v < h[i] ? m0v : h[i];
          }
          if ((int)m0v >= t) break;
        }
      }
      __syncthreads();
      asm volatile("" ::: "memory");   // pin Hin loads below the barrier
    }

    // ---- Hin: 16 PLAIN loads (L2-cached)
    bf16x8 areg[16];
    const u16* arow = Hin + (size_t)(nw0 + l15) * 512 + l4 * 8;
#pragma unroll
    for (int kk = 0; kk < 16; ++kk) areg[kk] = *(const bf16x8*)(arow + kk * 32);

    f32x4 zero = {0.f, 0.f, 0.f, 0.f};
    f32x4 acc[3] = {zero, zero, zero};

    // ---- 48 MFMA: A = WHH frag from LDS, B = areg (h)
    const char* lwb = (const char*)lW + (l4 << 8) + (l15 << 4);
#pragma unroll
    for (int g = 0; g < 3; ++g) {
      const char* lwg = lwb + (size_t)(g * 16) * 1024;
#pragma unroll
      for (int kk = 0; kk < 16; ++kk) {
        bf16x8 a = *(const bf16x8*)(lwg + kk * 1024);
        acc[g] = __builtin_amdgcn_mfma_f32_16x16x32_bf16(a, areg[kk], acc[g], 0, 0, 0);
      }
    }

    // ---- epilogue: gates (fast tanh), h update, one 8B sc1 store ----
    u32 pk0 = 0, pk1 = 0;
#pragma unroll
    for (int v = 0; v < 4; ++v) {
      float r = sigm(gi_get(giu[0], v) + acc[0][v] + bb[0][v]);
      float z = sigm(gi_get(giu[1], v) + acc[1][v] + bb[1][v]);
      float nn = ftanh(gi_get(giu[2], v) + r * (acc[2][v] + bb[2][v]));
      float h = (1.0f - z) * nn + z * hreg[v];
      hreg[v] = h;
      u32 hb = (u32)f2bf(h);
      if (v == 0) pk0 = hb;
      else if (v == 1) pk0 |= hb << 16;
      else if (v == 2) pk1 = hb;
      else pk1 |= hb << 16;
    }
    uint2 pk; pk.x = pk0; pk.y = pk1;
    store_cc_d2(Hout + (size_t)(nw0 + l15) * 512 + j0 + jt4, pk);

    if (t < T_ - 1) {
      WAITVM0();         // own sc1 stores visible at LLC
      __syncthreads();   // all threads of WG drained
      if (tid == 0) store_cc_u32(bmt + jt, (u32)(t + 1));
    }
  }
}

// ---------------- phase-C: heads + h expand + probs + p (+ last-step dup) ----------------
__global__ __launch_bounds__(256) void heads_kernel(
    const u16* __restrict__ Hsave,
    const float* __restrict__ Wc, const float* __restrict__ bc,
    const float* __restrict__ Wa, const float* __restrict__ ba,
    const int* __restrict__ actions, const int* __restrict__ qpre,
    const int* __restrict__ qpost, float* __restrict__ out)
{
  int row = blockIdx.x * 4 + (threadIdx.x >> 6);
  int lane = threadIdx.x & 63;
  bool last = row >= (T_ - 1) * N_;
  const int DUP = N_ * S_;
  const u16x8 hv8 = *(const u16x8*)(Hsave + (size_t)(N_ + row) * 512 + lane * 8);
  float* oh = out + (size_t)row * S_ + 2 + lane * 8;
  float pc = 0, p0 = 0, p1 = 0, p2 = 0, p3 = 0;
#pragma unroll
  for (int jj = 0; jj < 8; ++jj) {
    int k = lane * 8 + jj;
    float hv = bf2f(hv8[jj]);
    oh[jj] = hv;
    if (last) oh[DUP + jj] = hv;
    pc += hv * Wc[k];
    p0 += hv * Wa[k];
    p1 += hv * Wa[512 + k];
    p2 += hv * Wa[1024 + k];
    p3 += hv * Wa[1536 + k];
  }
#pragma unroll
  for (int m = 1; m < 64; m <<= 1) {
    pc += __shfl_xor(pc, m);
    p0 += __shfl_xor(p0, m);
    p1 += __shfl_xor(p1, m);
    p2 += __shfl_xor(p2, m);
    p3 += __shfl_xor(p3, m);
  }
  float v = pc + bc[0];
  float k0 = p0 + ba[0], k1 = p1 + ba[1], k2 = p2 + ba[2], k3 = p3 + ba[3];
  float mx = fmaxf(k0, fmaxf(k1, k2));
  float e0 = __expf(k0 - mx), e1 = __expf(k1 - mx), e2 = __expf(k2 - mx);
  float es = e0 + e1 + e2;
  float l0 = e0 / es, l1 = e1 / es, l2 = e2 / es;
  float no = sigm(k3);
  float total = (1.0f - no) * (l0 + l1 + l2) + no;
  float sc = (1.0f - no) / total;
  int q = qpre[row], qp = qpost[row];
  int a = actions[row];
  if (lane == 0) {
    out[(size_t)row * S_] = (float)a;
    out[(size_t)row * S_ + 1] = v;
    if (last) {
      out[(size_t)row * S_ + DUP] = (float)a;
      out[(size_t)row * S_ + DUP + 1] = v;
    }
  }
  float* pr = out + (size_t)row * S_ + 2 + H_;
  for (int c = lane; c < L_ + 1; c += 64) {
    float val;
    if (c == L_) val = no / total;
    else {
      val = 0.f;
      if (q == 0)            { if (c == 0) val = l1 + l2; else if (c == 1) val = l0; }
      else if (q == L_ - 1)  { if (c == L_ - 2) val = l2; else if (c == L_ - 1) val = l0 + l1; }
      else                   { if (c == q - 1) val = l2; else if (c == q) val = l1; else if (c == q + 1) val = l0; }
      val *= sc;
    }
    pr[c] = val;
    if (last) pr[DUP + c] = val;
  }
  float* pp = pr + (L_ + 1);
  for (int c = lane; c < L_; c += 64) {
    float val = (c == qp) ? 1.0f : 0.0f;
    pp[c] = val;
    if (last) pp[DUP + c] = val;
  }
}

// ---------------- launch ----------------
extern "C" void kernel_launch(void* const* d_in, const int* in_sizes, int n_in,
                              void* d_out, int out_size, void* d_ws, size_t ws_size,
                              hipStream_t stream) {
  const float* cond = (const float*)d_in[0];
  const float* hxs  = (const float*)d_in[1];
  const float* emb  = (const float*)d_in[2];
  const float* W0   = (const float*)d_in[3];
  const float* b0   = (const float*)d_in[4];
  const float* W1   = (const float*)d_in[5];
  const float* b1   = (const float*)d_in[6];
  const float* W2   = (const float*)d_in[7];
  const float* b2   = (const float*)d_in[8];
  const float* Wih  = (const float*)d_in[9];
  const float* bih  = (const float*)d_in[10];
  const float* Whh  = (const float*)d_in[11];
  const float* bhh  = (const float*)d_in[12];
  const float* Wc   = (const float*)d_in[13];
  const float* bc   = (const float*)d_in[14];
  const float* Wa   = (const float*)d_in[15];
  const float* ba   = (const float*)d_in[16];
  const int* lines   = (const int*)d_in[17];
  const int* actions = (const int*)d_in[18];
  float* out = (float*)d_out;

  char* ws = (char*)d_ws;
  size_t off = 0;
  auto alloc = [&](size_t bytes) {
    char* p = ws + off;
    off += (bytes + 255) & ~(size_t)255;
    return p;
  };
  u16* P = (u16*)alloc((size_t)TN_ * 576 * 2);    // Abuf, then X2
  u16* Q = (u16*)alloc((size_t)TN_ * 512 * 2);    // X1, then X3
  u16* GIb = (u16*)alloc((size_t)TN_ * 1536 * 2); // gi (201MB)
  u16* Abuf = P;
  u16* X1 = Q;
  u16* X2 = P;
  u16* X3 = Q;
  // weight regions contiguous (each a multiple of 128 elements)
  u16* W0b = (u16*)alloc((size_t)512 * 576 * 2);
  u16* W1b = (u16*)alloc((size_t)512 * 512 * 2);
  u16* W2b = (u16*)alloc((size_t)512 * 512 * 2);
  u16* WIHb = (u16*)alloc((size_t)1536 * 512 * 2);
  u16* WHHb = (u16*)alloc((size_t)1536 * 512 * 2);
  u16* EMBb = (u16*)alloc((size_t)64 * 512 * 2);
  int* qpre  = (int*)alloc((size_t)TN_ * 4);
  int* qpost = (int*)alloc((size_t)TN_ * 4);
  u16* Hsave = (u16*)alloc((size_t)(T_ + 1) * N_ * 512 * 2);  // 68MB
  int* bar = (int*)alloc((size_t)16 * 32 * 4);

  hipMemsetAsync(bar, 0, (size_t)16 * 32 * 4, stream);

  cast_all<<<(CTOT + 255) / 256, 256, 0, stream>>>(W0, W1, W2, Wih, Whh, emb, W0b);
  qscan<<<256, 256, 0, stream>>>(hxs, actions, qpre, qpost);
  hbf_init<<<(N_ * 512 + 255) / 256, 256, 0, stream>>>(hxs, Hsave);
  build_abuf<<<TN_ / 4, 256, 0, stream>>>(cond, EMBb, lines, qpre, Abuf);

  gemm_nt<<<dim3(4, 512), 256, 0, stream>>>(Abuf, 576, W0b, 576, b0, X1, 512, 576, 1);
  gemm_nt<<<dim3(4, 512), 256, 0, stream>>>(X1, 512, W1b, 512, b1, X2, 512, 512, 1);
  gemm_nt<<<dim3(4, 512), 256, 0, stream>>>(X2, 512, W2b, 512, b2, X3, 512, 512, 1);
  gemm_nt<<<dim3(12, 512), 256, 0, stream>>>(X3, 512, WIHb, 512, bih, GIb, 1536, 512, 0);

  gru_persistent<<<512, 256, 0, stream>>>(GIb, WHHb, Hsave, hxs, bhh, bar);

  heads_kernel<<<TN_ / 4, 256, 0, stream>>>(Hsave, Wc, bc, Wa, ba, actions, qpre, qpost, out);
}

// Round 12
// 1110.514 us; speedup vs baseline: 1.2135x; 1.2135x over previous
//
#include <hip/hip_runtime.h>
#include <hip/hip_bf16.h>
#include <stdint.h>

#define T_ 64
#define N_ 1024
#define L_ 128
#define H_ 512
#define C_ 64
#define S_ 771          // 1 + 1 + H + (L+1) + L
#define TN_ (T_*N_)

typedef unsigned short u16;
typedef unsigned int u32;
typedef float f32x4 __attribute__((ext_vector_type(4)));
typedef __bf16 bf16x8 __attribute__((ext_vector_type(8)));
typedef u16 u16x8 __attribute__((ext_vector_type(8)));
typedef u32 u32x4 __attribute__((ext_vector_type(4)));

#define WAITVM0() do { asm volatile("s_waitcnt vmcnt(0)" ::: "memory"); \
                       __builtin_amdgcn_sched_barrier(0); } while (0)

__device__ __forceinline__ u16 f2bf(float f) {
  u32 u = __float_as_uint(f);
  u32 r = (u + 0x7FFFu + ((u >> 16) & 1u)) >> 16;
  return (u16)r;
}
__device__ __forceinline__ float bf2f(u16 u) {
  return __uint_as_float(((u32)u) << 16);
}
__device__ __forceinline__ void gload16(const void* g, void* l) {
  __builtin_amdgcn_global_load_lds((const __attribute__((address_space(1))) u32*)g,
                                   (__attribute__((address_space(3))) u32*)l, 16, 0, 0);
}
__device__ __forceinline__ float sigm(float x) { return 1.0f / (1.0f + __expf(-x)); }
// fast tanh: 1 - 2/(1+e^{2x}); correct limits at +-inf (R11-verified absmax-neutral)
__device__ __forceinline__ float ftanh(float x) {
  return 1.0f - 2.0f / (1.0f + __expf(2.0f * x));
}

__device__ __forceinline__ u32x4 load_cc4(const int* p) {
  u32x4 v;
  asm volatile("global_load_dwordx4 %0, %1, off sc0 sc1" : "=v"(v) : "v"(p) : "memory");
  return v;
}
__device__ __forceinline__ void store_cc_d2(u16* p, uint2 val) {
  asm volatile("global_store_dwordx2 %0, %1, off sc0 sc1" :: "v"(p), "v"(val) : "memory");
}
__device__ __forceinline__ void store_cc_u32(int* p, u32 val) {
  asm volatile("global_store_dword %0, %1, off sc0 sc1" :: "v"(p), "v"(val) : "memory");
}
__device__ __forceinline__ float gi_get(uint2 u, int v) {
  u32 w = (v < 2) ? u.x : u.y;
  u16 h = (v & 1) ? (u16)(w >> 16) : (u16)(w & 0xffffu);
  return bf2f(h);
}

// ---------------- prep kernels ----------------
#define CA0 294912      // W0  512*576
#define CA1 557056      // W1  +512*512
#define CA2 819200      // W2  +512*512
#define CA3 1605632     // Wih +1536*512
#define CA4 2392064     // Whh +1536*512
#define CTOT 2424832    // emb +64*512
__global__ void cast_all(const float* __restrict__ W0, const float* __restrict__ W1,
                         const float* __restrict__ W2, const float* __restrict__ Wih,
                         const float* __restrict__ Whh, const float* __restrict__ emb,
                         u16* __restrict__ dst) {
  int i = blockIdx.x * 256 + threadIdx.x;
  if (i >= CTOT) return;
  float v;
  if (i < CA0)      v = W0[i];
  else if (i < CA1) v = W1[i - CA0];
  else if (i < CA2) v = W2[i - CA1];
  else if (i < CA3) v = Wih[i - CA2];
  else if (i < CA4) v = Whh[i - CA3];
  else              v = emb[i - CA4];
  dst[i] = f2bf(v);
}

__global__ void qscan(const float* __restrict__ hxs, const int* __restrict__ actions,
                      int* __restrict__ qpre, int* __restrict__ qpost) {
  int wave = threadIdx.x >> 6, lane = threadIdx.x & 63;
  int n = blockIdx.x * 4 + wave;
  int a_l = actions[lane * N_ + n];
  bool nz = false;
  for (int s = lane; s < S_; s += 64) nz |= (hxs[(size_t)n * S_ + s] != 0.0f);
  unsigned long long bal = __ballot(nz);
  int q = 0;
  if (bal) {
    float best = -3.4e38f; int bi = L_;
    for (int l = lane; l < L_; l += 64) {
      float v = hxs[(size_t)n * S_ + 2 + H_ + (L_ + 1) + l];
      if (v > best) { best = v; bi = l; }
    }
    for (int m = 32; m; m >>= 1) {
      float ob = __shfl_xor(best, m); int oi = __shfl_xor(bi, m);
      if (ob > best || (ob == best && oi < bi)) { best = ob; bi = oi; }
    }
    q = (bi < L_) ? bi : 0;
  }
  for (int t = 0; t < T_; ++t) {
    int a = __shfl(a_l, t);
    if (lane == 0) {
      qpre[t * N_ + n] = q;
      if (a < L_) q = a;
      qpost[t * N_ + n] = q;
    }
  }
}

__global__ void hbf_init(const float* __restrict__ hxs, u16* __restrict__ hsave0) {
  int i = blockIdx.x * 256 + threadIdx.x;
  if (i >= N_ * H_) return;
  int n = i >> 9, j = i & 511;
  hsave0[i] = f2bf(hxs[(size_t)n * S_ + 2 + j]);
}

// A = [cond_t | embb[lines[n, qpre]]] as bf16 (TN x 576); one wave per row
__global__ void build_abuf(const float* __restrict__ cond, const u16* __restrict__ embb,
                           const int* __restrict__ lines, const int* __restrict__ qpre,
                           u16* __restrict__ abuf) {
  int row = blockIdx.x * 4 + (threadIdx.x >> 6);
  int lane = threadIdx.x & 63;
  int n = row & (N_ - 1);
  int q = qpre[row];
  int line = lines[n * L_ + q];
  abuf[(size_t)row * 576 + lane] = f2bf(cond[(size_t)row * 64 + lane]);
  const u16* er = embb + (size_t)line * H_;
  u16* ar = abuf + (size_t)row * 576 + 64;
  for (int j = lane; j < H_; j += 64) ar[j] = er[j];
}

// ---------------- phase-A GEMM ----------------
#define BM 128
#define BN 128
#define BK 64
__global__ __launch_bounds__(256) void gemm_nt(
    const u16* __restrict__ A, int lda,
    const u16* __restrict__ B, int ldb,
    const float* __restrict__ bias,
    u16* __restrict__ C, int ldc,
    int K, int relu)
{
  __shared__ __align__(16) u16 lA[BM * BK];
  __shared__ __align__(16) u16 lB[BN * BK];
  int tid = threadIdx.x;
  int lane = tid & 63;
  int wave = tid >> 6;
  int wm = wave >> 1, wn = wave & 1;
  int m0 = blockIdx.y * BM;
  int n0 = blockIdx.x * BN;

  f32x4 acc[4][4];
  f32x4 zero = {0.f, 0.f, 0.f, 0.f};
#pragma unroll
  for (int i = 0; i < 4; ++i)
#pragma unroll
    for (int j = 0; j < 4; ++j) acc[i][j] = zero;

  int nkt = K / BK;
  for (int kt = 0; kt < nkt; ++kt) {
#pragma unroll
    for (int it = 0; it < 4; ++it) {
      int s = it * 256 + tid;
      int row = s >> 3, cs = s & 7;
      gload16(A + (size_t)(m0 + row) * lda + kt * BK + cs * 8,
              lA + (size_t)(it * 256 + (tid & ~63)) * 8);
      gload16(B + (size_t)(n0 + row) * ldb + kt * BK + cs * 8,
              lB + (size_t)(it * 256 + (tid & ~63)) * 8);
    }
    __syncthreads();
#pragma unroll
    for (int ks = 0; ks < 2; ++ks) {
      bf16x8 af[4], bfr[4];
#pragma unroll
      for (int fm = 0; fm < 4; ++fm) {
        int rowa = wm * 64 + fm * 16 + (lane & 15);
        af[fm] = *(const bf16x8*)&lA[rowa * BK + ks * 32 + ((lane >> 4) << 3)];
      }
#pragma unroll
      for (int fn = 0; fn < 4; ++fn) {
        int rowb = wn * 64 + fn * 16 + (lane & 15);
        bfr[fn] = *(const bf16x8*)&lB[rowb * BK + ks * 32 + ((lane >> 4) << 3)];
      }
#pragma unroll
      for (int fm = 0; fm < 4; ++fm)
#pragma unroll
        for (int fn = 0; fn < 4; ++fn)
          acc[fm][fn] = __builtin_amdgcn_mfma_f32_16x16x32_bf16(af[fm], bfr[fn], acc[fm][fn], 0, 0, 0);
    }
    __syncthreads();
  }
#pragma unroll
  for (int fm = 0; fm < 4; ++fm) {
#pragma unroll
    for (int fn = 0; fn < 4; ++fn) {
      int col = n0 + wn * 64 + fn * 16 + (lane & 15);
      float b = bias[col];
#pragma unroll
      for (int v = 0; v < 4; ++v) {
        int row = m0 + wm * 64 + fm * 16 + ((lane >> 4) << 2) + v;
        float val = acc[fm][fn][v] + b;
        if (relu) val = fmaxf(val, 0.0f);
        C[(size_t)row * ldc + col] = f2bf(val);
      }
    }
  }
}

// ---------------- phase-B: persistent GRU recurrence (R10-exact config) ----------------
// 256 WGs = 16 mt (64 n) x 16 jt (32 j). 96KB LDS, 1 WG/CU, barrier fan-in 16
// (R11 showed fan-in 32 + 2WG/CU regresses). Waves: 4 n-subtiles x full 32 j.
// WHH chunk-transposed LDS (0-conflict, R9/R10). Hout/flags sc0sc1; Hin plain L2.
__global__ __launch_bounds__(256, 1) void gru_persistent(
    const u16* __restrict__ GI,    // (TN,1536) bf16
    const u16* __restrict__ WHH,   // (1536,512) bf16
    u16* __restrict__ Hsave,       // (T_+1, N_, 512) bf16; slot 0 = h_init
    const float* __restrict__ hxs, // initial h f32 at [n*S_+2+j]
    const float* __restrict__ bhh, // (1536)
    int* __restrict__ bar)         // [16][16] zeroed before launch
{
  __shared__ __align__(1024) u16 lW[96 * 512];   // 96KB
  int tid = threadIdx.x;
  int lane = tid & 63;
  int wave = tid >> 6;
  int bid = blockIdx.x;
  int mt = bid & 15, jt = bid >> 4;
  int l15 = lane & 15, l4 = lane >> 4;
  int nw0 = mt * 64 + wave * 16;       // wave's 16 n-rows
  int j0 = jt * 32;                    // WG's j base (32 cols, fn halves)
  int jt4 = l4 * 4;

  // ---- stage WHH slice into LDS, chunk-transposed
  for (int c = wave; c < 96; c += 4) {
    int wjs = c / 48;
    int rem = c - wjs * 48;
    int g = rem >> 4, kk = rem & 15;
    const u16* src = WHH + ((size_t)(g * 512 + j0 + wjs * 16 + l15)) * 512 + kk * 32 + l4 * 8;
    gload16(src, (char*)lW + c * 1024);
  }

  // ---- per-lane constants
  float bb[2][3][4];
  float hreg[2][4];
#pragma unroll
  for (int fn = 0; fn < 2; ++fn) {
#pragma unroll
    for (int g = 0; g < 3; ++g)
#pragma unroll
      for (int v = 0; v < 4; ++v) bb[fn][g][v] = bhh[g * 512 + j0 + fn * 16 + jt4 + v];
#pragma unroll
    for (int v = 0; v < 4; ++v)
      hreg[fn][v] = hxs[(size_t)(nw0 + l15) * S_ + 2 + j0 + fn * 16 + jt4 + v];
  }

  WAITVM0();
  __syncthreads();

  int* bmt = bar + mt * 16;

  for (int t = 0; t < T_; ++t) {
    const u16* Hin = Hsave + (size_t)t * (N_ * 512);
    u16* Hout = Hsave + (size_t)(t + 1) * (N_ * 512);
    const size_t tb = (size_t)t * N_;

    // ---- gi loads (plain, cached), issued before the spin so latency hides
    const u16* girow = GI + (tb + nw0 + l15) * 1536;
    uint2 giu[2][3];
#pragma unroll
    for (int fn = 0; fn < 2; ++fn)
#pragma unroll
      for (int g = 0; g < 3; ++g)
        giu[fn][g] = *(const uint2*)(girow + g * 512 + j0 + fn * 16 + jt4);

    if (t > 0) {
      if (tid == 0) {
        for (;;) {
          u32x4 a = load_cc4(bmt), b = load_cc4(bmt + 4);
          u32x4 c = load_cc4(bmt + 8), d = load_cc4(bmt + 12);
          WAITVM0();
          u32 m0v = a[0];
#pragma unroll
          for (int i = 1; i < 4; ++i) m0v = m0v < a[i] ? m0v : a[i];
#pragma unroll
          for (int i = 0; i < 4; ++i) { m0v = m0v < b[i] ? m0v : b[i];
                                        m0v = m0v < c[i] ? m0v : c[i];
                                        m0v = m0v < d[i] ? m0v : d[i]; }
          if ((int)m0v >= t) break;
        }
      }
      __syncthreads();
      asm volatile("" ::: "memory");   // pin Hin loads below the barrier
    }

    // ---- Hin: 16 PLAIN loads (L2-cached; lines fresh by construction)
    bf16x8 areg[16];
    const u16* arow = Hin + (size_t)(nw0 + l15) * 512 + l4 * 8;
#pragma unroll
    for (int kk = 0; kk < 16; ++kk) areg[kk] = *(const bf16x8*)(arow + kk * 32);

    f32x4 zero = {0.f, 0.f, 0.f, 0.f};
    f32x4 acc[2][3] = {{zero, zero, zero}, {zero, zero, zero}};

    // ---- 96 MFMA: A = WHH frag from LDS (fn half), B = areg (h)
    const char* lwb = (const char*)lW + (l4 << 8) + (l15 << 4);
#pragma unroll
    for (int fn = 0; fn < 2; ++fn)
#pragma unroll
      for (int g = 0; g < 3; ++g) {
        const char* lwg = lwb + (size_t)(fn * 48 + g * 16) * 1024;
#pragma unroll
        for (int kk = 0; kk < 16; ++kk) {
          bf16x8 a = *(const bf16x8*)(lwg + kk * 1024);
          acc[fn][g] = __builtin_amdgcn_mfma_f32_16x16x32_bf16(a, areg[kk], acc[fn][g], 0, 0, 0);
        }
      }

    // ---- epilogue: gates (fast tanh), h update, one 8B sc1 store per fn ----
#pragma unroll
    for (int fn = 0; fn < 2; ++fn) {
      u32 pk0 = 0, pk1 = 0;
#pragma unroll
      for (int v = 0; v < 4; ++v) {
        float r = sigm(gi_get(giu[fn][0], v) + acc[fn][0][v] + bb[fn][0][v]);
        float z = sigm(gi_get(giu[fn][1], v) + acc[fn][1][v] + bb[fn][1][v]);
        float nn = ftanh(gi_get(giu[fn][2], v) + r * (acc[fn][2][v] + bb[fn][2][v]));
        float h = (1.0f - z) * nn + z * hreg[fn][v];
        hreg[fn][v] = h;
        u32 hb = (u32)f2bf(h);
        if (v == 0) pk0 = hb;
        else if (v == 1) pk0 |= hb << 16;
        else if (v == 2) pk1 = hb;
        else pk1 |= hb << 16;
      }
      uint2 pk; pk.x = pk0; pk.y = pk1;
      store_cc_d2(Hout + (size_t)(nw0 + l15) * 512 + j0 + fn * 16 + jt4, pk);
    }

    if (t < T_ - 1) {
      WAITVM0();         // own sc1 stores visible at LLC
      __syncthreads();   // all threads of WG drained
      if (tid == 0) store_cc_u32(bmt + jt, (u32)(t + 1));
    }
  }
}

// ---------------- phase-C: heads + h expand + probs + p (+ last-step dup) ----------------
__global__ __launch_bounds__(256) void heads_kernel(
    const u16* __restrict__ Hsave,
    const float* __restrict__ Wc, const float* __restrict__ bc,
    const float* __restrict__ Wa, const float* __restrict__ ba,
    const int* __restrict__ actions, const int* __restrict__ qpre,
    const int* __restrict__ qpost, float* __restrict__ out)
{
  int row = blockIdx.x * 4 + (threadIdx.x >> 6);
  int lane = threadIdx.x & 63;
  bool last = row >= (T_ - 1) * N_;
  const int DUP = N_ * S_;
  const u16x8 hv8 = *(const u16x8*)(Hsave + (size_t)(N_ + row) * 512 + lane * 8);
  float* oh = out + (size_t)row * S_ + 2 + lane * 8;
  float pc = 0, p0 = 0, p1 = 0, p2 = 0, p3 = 0;
#pragma unroll
  for (int jj = 0; jj < 8; ++jj) {
    int k = lane * 8 + jj;
    float hv = bf2f(hv8[jj]);
    oh[jj] = hv;
    if (last) oh[DUP + jj] = hv;
    pc += hv * Wc[k];
    p0 += hv * Wa[k];
    p1 += hv * Wa[512 + k];
    p2 += hv * Wa[1024 + k];
    p3 += hv * Wa[1536 + k];
  }
#pragma unroll
  for (int m = 1; m < 64; m <<= 1) {
    pc += __shfl_xor(pc, m);
    p0 += __shfl_xor(p0, m);
    p1 += __shfl_xor(p1, m);
    p2 += __shfl_xor(p2, m);
    p3 += __shfl_xor(p3, m);
  }
  float v = pc + bc[0];
  float k0 = p0 + ba[0], k1 = p1 + ba[1], k2 = p2 + ba[2], k3 = p3 + ba[3];
  float mx = fmaxf(k0, fmaxf(k1, k2));
  float e0 = __expf(k0 - mx), e1 = __expf(k1 - mx), e2 = __expf(k2 - mx);
  float es = e0 + e1 + e2;
  float l0 = e0 / es, l1 = e1 / es, l2 = e2 / es;
  float no = sigm(k3);
  float total = (1.0f - no) * (l0 + l1 + l2) + no;
  float sc = (1.0f - no) / total;
  int q = qpre[row], qp = qpost[row];
  int a = actions[row];
  if (lane == 0) {
    out[(size_t)row * S_] = (float)a;
    out[(size_t)row * S_ + 1] = v;
    if (last) {
      out[(size_t)row * S_ + DUP] = (float)a;
      out[(size_t)row * S_ + DUP + 1] = v;
    }
  }
  float* pr = out + (size_t)row * S_ + 2 + H_;
  for (int c = lane; c < L_ + 1; c += 64) {
    float val;
    if (c == L_) val = no / total;
    else {
      val = 0.f;
      if (q == 0)            { if (c == 0) val = l1 + l2; else if (c == 1) val = l0; }
      else if (q == L_ - 1)  { if (c == L_ - 2) val = l2; else if (c == L_ - 1) val = l0 + l1; }
      else                   { if (c == q - 1) val = l2; else if (c == q) val = l1; else if (c == q + 1) val = l0; }
      val *= sc;
    }
    pr[c] = val;
    if (last) pr[DUP + c] = val;
  }
  float* pp = pr + (L_ + 1);
  for (int c = lane; c < L_; c += 64) {
    float val = (c == qp) ? 1.0f : 0.0f;
    pp[c] = val;
    if (last) pp[DUP + c] = val;
  }
}

// ---------------- launch ----------------
extern "C" void kernel_launch(void* const* d_in, const int* in_sizes, int n_in,
                              void* d_out, int out_size, void* d_ws, size_t ws_size,
                              hipStream_t stream) {
  const float* cond = (const float*)d_in[0];
  const float* hxs  = (const float*)d_in[1];
  const float* emb  = (const float*)d_in[2];
  const float* W0   = (const float*)d_in[3];
  const float* b0   = (const float*)d_in[4];
  const float* W1   = (const float*)d_in[5];
  const float* b1   = (const float*)d_in[6];
  const float* W2   = (const float*)d_in[7];
  const float* b2   = (const float*)d_in[8];
  const float* Wih  = (const float*)d_in[9];
  const float* bih  = (const float*)d_in[10];
  const float* Whh  = (const float*)d_in[11];
  const float* bhh  = (const float*)d_in[12];
  const float* Wc   = (const float*)d_in[13];
  const float* bc   = (const float*)d_in[14];
  const float* Wa   = (const float*)d_in[15];
  const float* ba   = (const float*)d_in[16];
  const int* lines   = (const int*)d_in[17];
  const int* actions = (const int*)d_in[18];
  float* out = (float*)d_out;

  char* ws = (char*)d_ws;
  size_t off = 0;
  auto alloc = [&](size_t bytes) {
    char* p = ws + off;
    off += (bytes + 255) & ~(size_t)255;
    return p;
  };
  u16* P = (u16*)alloc((size_t)TN_ * 576 * 2);    // Abuf, then X2
  u16* Q = (u16*)alloc((size_t)TN_ * 512 * 2);    // X1, then X3
  u16* GIb = (u16*)alloc((size_t)TN_ * 1536 * 2); // gi (201MB)
  u16* Abuf = P;
  u16* X1 = Q;
  u16* X2 = P;
  u16* X3 = Q;
  // weight regions contiguous (each a multiple of 128 elements)
  u16* W0b = (u16*)alloc((size_t)512 * 576 * 2);
  u16* W1b = (u16*)alloc((size_t)512 * 512 * 2);
  u16* W2b = (u16*)alloc((size_t)512 * 512 * 2);
  u16* WIHb = (u16*)alloc((size_t)1536 * 512 * 2);
  u16* WHHb = (u16*)alloc((size_t)1536 * 512 * 2);
  u16* EMBb = (u16*)alloc((size_t)64 * 512 * 2);
  int* qpre  = (int*)alloc((size_t)TN_ * 4);
  int* qpost = (int*)alloc((size_t)TN_ * 4);
  u16* Hsave = (u16*)alloc((size_t)(T_ + 1) * N_ * 512 * 2);  // 68MB
  int* bar = (int*)alloc((size_t)16 * 16 * 4);

  hipMemsetAsync(bar, 0, (size_t)16 * 16 * 4, stream);

  cast_all<<<(CTOT + 255) / 256, 256, 0, stream>>>(W0, W1, W2, Wih, Whh, emb, W0b);
  qscan<<<256, 256, 0, stream>>>(hxs, actions, qpre, qpost);
  hbf_init<<<(N_ * 512 + 255) / 256, 256, 0, stream>>>(hxs, Hsave);
  build_abuf<<<TN_ / 4, 256, 0, stream>>>(cond, EMBb, lines, qpre, Abuf);

  gemm_nt<<<dim3(4, 512), 256, 0, stream>>>(Abuf, 576, W0b, 576, b0, X1, 512, 576, 1);
  gemm_nt<<<dim3(4, 512), 256, 0, stream>>>(X1, 512, W1b, 512, b1, X2, 512, 512, 1);
  gemm_nt<<<dim3(4, 512), 256, 0, stream>>>(X2, 512, W2b, 512, b2, X3, 512, 512, 1);
  gemm_nt<<<dim3(12, 512), 256, 0, stream>>>(X3, 512, WIHb, 512, bih, GIb, 1536, 512, 0);

  gru_persistent<<<256, 256, 0, stream>>>(GIb, WHHb, Hsave, hxs, bhh, bar);

  heads_kernel<<<TN_ / 4, 256, 0, stream>>>(Hsave, Wc, bc, Wa, ba, actions, qpre, qpost, out);
}